// Round 7
// baseline (383.672 us; speedup 1.0000x reference)
//
#include <hip/hip_runtime.h>
#include <math.h>

typedef unsigned int uint;
typedef unsigned short ushort;

typedef __attribute__((ext_vector_type(8))) __bf16 bf16x8;
typedef __attribute__((ext_vector_type(16))) float floatx16;

#define NFEAT 327680   // 256*1280 feats (bf16)
#define NW    491520   // 128*3840 W (bf16)
#define NWT   327680   // Wt uints (128*2560 bf16 = 640 KB, fragment-ordered)
// ws: fB bf16[NFEAT] | wB bf16[NW] | stats f32[16] | Aoi f32[128*256] | Wt bf16[2*NWT]

union U4B8 { uint4 u; bf16x8 b; };

__device__ inline ushort f2b(float f) {
  uint u = __float_as_uint(f);
  u += 0x7fffu + ((u >> 16) & 1u);   // RNE
  return (ushort)(u >> 16);
}
__device__ inline float blo(uint u) { return __uint_as_float(u << 16); }
__device__ inline float bhi(uint u) { return __uint_as_float(u & 0xffff0000u); }

#if __has_builtin(__builtin_amdgcn_cvt_pk_bf16_f32)
typedef __attribute__((ext_vector_type(2))) __bf16 bf16x2;
__device__ inline uint cvtpk(float a, float b) {
  bf16x2 r = __builtin_amdgcn_cvt_pk_bf16_f32(a, b);
  return *(uint*)&r;
}
__device__ inline uint cvtpk_abs(float a, float b) { return cvtpk(fabsf(a), fabsf(b)); }
#else
__device__ inline uint cvtpk(float a, float b) {   // round-half-up fallback
  uint au = __float_as_uint(a) + 0x8000u;
  uint bu = __float_as_uint(b) + 0x8000u;
  return __builtin_amdgcn_perm(bu, au, 0x07060302u);
}
__device__ inline uint cvtpk_abs(float a, float b) { return cvtpk(a, b) & 0x7fff7fffu; }
#endif

// ---------------- prep: bf16 conversions, Wt fragment layout, zero stats/Aoi ----
// Wt fragment f = cc*16 + st*8 + term*4 + rg  (1 KB each = 256 uints):
//   uint q in frag: lane l = q>>2, t = q&3
//   -> W row = rg*32 + (l&31), k = cc*32 + st*16 + (l>>5)*8 + t*2, col = 1280 + term*1280 + k
__global__ void prep_kernel(const float* __restrict__ feats,
                            const float* __restrict__ W,
                            ushort* __restrict__ fB,
                            ushort* __restrict__ wB,
                            float* __restrict__ stats,
                            float* __restrict__ Aoi,
                            uint* __restrict__ Wt) {
  int idx = blockIdx.x * 256 + threadIdx.x;   // 4480*256 = 819200 + 327680
  if (blockIdx.x == 0 && threadIdx.x < 16) stats[threadIdx.x] = 0.0f;
  if (idx < 32768) Aoi[idx] = 0.0f;
  if (idx < NFEAT) {
    fB[idx] = f2b(feats[idx]);
  } else if (idx < NFEAT + NW) {
    wB[idx - NFEAT] = f2b(W[idx - NFEAT]);
  } else {
    const uint u = idx - (NFEAT + NW);       // [0, NWT)
    const uint frag = u >> 8, q = u & 255;
    const uint rg = frag & 3, term = (frag >> 2) & 1, st = (frag >> 3) & 1, cc = frag >> 4;
    const uint l = q >> 2, t = q & 3;
    const uint row = rg * 32 + (l & 31);
    const uint k = cc * 32 + st * 16 + (l >> 5) * 8 + t * 2;
    const float* src = W + row * 3840 + 1280 + term * 1280 + k;
    Wt[u] = (uint)f2b(src[0]) | ((uint)f2b(src[1]) << 16);
  }
}

// ---------------- A[o,i] = sum_c Wa[o,c]*f[i,c] ----------------
__global__ __launch_bounds__(256, 2) void gemma_kernel(
    const ushort* __restrict__ fB, const ushort* __restrict__ wB,
    float* __restrict__ Aoi) {
  __shared__ float red[4][4096];
  const int tid = threadIdx.x, lane = tid & 63, w = tid >> 6;
  const int i0 = (blockIdx.x >> 2) << 5;
  const int kq = blockIdx.x & 3;
  const int rr = lane & 31, half = lane >> 5;
  floatx16 a4[4];
  #pragma unroll
  for (int ot = 0; ot < 4; ++ot)
    #pragma unroll
    for (int r = 0; r < 16; ++r) a4[ot][r] = 0.0f;
  const int kbase = kq * 320 + w * 80 + half * 8;
  #pragma unroll
  for (int ks = 0; ks < 5; ++ks) {
    const int k = kbase + ks * 16;
    U4B8 bf; bf.u = *(const uint4*)(fB + (i0 + rr) * 1280 + k);
    #pragma unroll
    for (int ot = 0; ot < 4; ++ot) {
      U4B8 af; af.u = *(const uint4*)(wB + (ot * 32 + rr) * 3840 + k);
      a4[ot] = __builtin_amdgcn_mfma_f32_32x32x16_bf16(af.b, bf.b, a4[ot], 0, 0, 0);
    }
  }
  #pragma unroll
  for (int ot = 0; ot < 4; ++ot)
    #pragma unroll
    for (int r = 0; r < 16; ++r) {
      const int orow = (r & 3) + 8 * (r >> 2) + 4 * half;
      red[w][(ot * 32 + orow) * 32 + rr] = a4[ot][r];
    }
  __syncthreads();
  for (int e = tid; e < 4096; e += 256) {
    float s = red[0][e] + red[1][e] + red[2][e] + red[3][e];
    atomicAdd(&Aoi[(e >> 5) * 256 + i0 + (e & 31)], s);
  }
}

// build diff/had B-fragments from fj bits + unpacked fi
__device__ inline void build(const uint4 vj, const float fi8[8], U4B8& d, U4B8& h) {
  uint ju[4] = {vj.x, vj.y, vj.z, vj.w};
  uint* pd = &d.u.x; uint* ph = &h.u.x;
  #pragma unroll
  for (int t = 0; t < 4; ++t) {
    float j0f = blo(ju[t]), j1f = bhi(ju[t]);
    float i0 = fi8[2 * t], i1 = fi8[2 * t + 1];
    pd[t] = cvtpk_abs(i0 - j0f, i1 - j1f);
    ph[t] = cvtpk(i0 * j0f, i1 * j1f);
  }
}

// ---------------- main fused GEMM: diff+had, K=2560, NO LDS / NO BARRIERS ----
// grid 1024: i = blk>>2, j0 = (blk&3)*64; 4 waves 2x2 (wo=(w>>1)*64, wm=(w&1)*32),
// wave tile 64o x 32m. W A-fragments loaded straight from L2-resident Wt
// (fragment-ordered, each load = contiguous 1 KB: base + lane*16). Waves are
// fully independent until the epilogue stats reduce.
__global__ __launch_bounds__(256, 4) void gemm_kernel(
    const ushort* __restrict__ fB, const uint* __restrict__ Wt,
    const float* __restrict__ bias, const float* __restrict__ Aoi,
    float* __restrict__ xout, float* __restrict__ stats) {
  __shared__ float sred[16];

  const int tid = threadIdx.x;
  const int blk = blockIdx.x;
  const int i_row = blk >> 2;
  const int j0 = (blk & 3) << 6;
  const int lane = tid & 63;
  const int w = tid >> 6;
  const int wo = (w >> 1) << 6;
  const int wm = (w & 1) << 5;
  const int rr = lane & 31;
  const int half = lane >> 5;
  const int rg0 = wo >> 5;           // 0 or 2

  // W fragment pointers (uint granularity): frag = cc*16 + st*8 + term*4 + rg
  // pw[st][term] -> frag(0, st, term, rg0) + lane*4 uints; ot adds 256, chunk adds 4096
  const uint* pw[2][2];
  #pragma unroll
  for (int st = 0; st < 2; ++st)
    #pragma unroll
    for (int term = 0; term < 2; ++term)
      pw[st][term] = Wt + (st * 8 + term * 4 + rg0) * 256 + lane * 4;

  const ushort* fip = fB + i_row * 1280 + half * 8;
  const ushort* fjp = fB + (j0 + wm + rr) * 1280 + half * 8;

  floatx16 acc[2];
  #pragma unroll
  for (int a = 0; a < 2; ++a)
    #pragma unroll
    for (int r = 0; r < 16; ++r) acc[a][r] = 0.0f;

  // prefetch fi/fj chunk 0
  uint4 vi[2], vj[2];
  #pragma unroll
  for (int st = 0; st < 2; ++st) {
    vi[st] = *(const uint4*)(fip + st * 16);
    vj[st] = *(const uint4*)(fjp + st * 16);
  }

  for (int cc = 0; cc < 40; ++cc) {
    // issue all 8 W-fragment loads for this chunk (coalesced 1 KB each)
    uint4 wf[2][2][2];   // [st][term][ot]
    #pragma unroll
    for (int st = 0; st < 2; ++st)
      #pragma unroll
      for (int term = 0; term < 2; ++term) {
        wf[st][term][0] = *(const uint4*)(pw[st][term]);
        wf[st][term][1] = *(const uint4*)(pw[st][term] + 256);
        pw[st][term] += 4096;
      }
    // prefetch fi/fj for next chunk
    uint4 vin[2], vjn[2];
    if (cc < 39) {
      const int cn = (cc + 1) << 5;
      #pragma unroll
      for (int st = 0; st < 2; ++st) {
        vin[st] = *(const uint4*)(fip + cn + st * 16);
        vjn[st] = *(const uint4*)(fjp + cn + st * 16);
      }
    }
    #pragma unroll
    for (int st = 0; st < 2; ++st) {
      float fi8[8];
      {
        uint iu[4] = {vi[st].x, vi[st].y, vi[st].z, vi[st].w};
        #pragma unroll
        for (int t = 0; t < 4; ++t) { fi8[2*t] = blo(iu[t]); fi8[2*t+1] = bhi(iu[t]); }
      }
      U4B8 dfr, hfr;
      build(vj[st], fi8, dfr, hfr);
      #pragma unroll
      for (int ot = 0; ot < 2; ++ot) {
        U4B8 ad, ah;
        ad.u = wf[st][0][ot];
        ah.u = wf[st][1][ot];
        acc[ot] = __builtin_amdgcn_mfma_f32_32x32x16_bf16(ad.b, dfr.b, acc[ot], 0, 0, 0);
        acc[ot] = __builtin_amdgcn_mfma_f32_32x32x16_bf16(ah.b, hfr.b, acc[ot], 0, 0, 0);
      }
    }
    if (cc < 39) {
      #pragma unroll
      for (int st = 0; st < 2; ++st) { vi[st] = vin[st]; vj[st] = vjn[st]; }
    }
  }

  // epilogue: add A[o,i]+A[o,j]+b[o], store, group stats
  float gs[2][2] = {{0.f, 0.f}, {0.f, 0.f}};
  float gq[2][2] = {{0.f, 0.f}, {0.f, 0.f}};
  const int jg = j0 + wm + rr;
  const int mglob = i_row * 256 + jg;
  #pragma unroll
  for (int ot = 0; ot < 2; ++ot) {
    #pragma unroll
    for (int r = 0; r < 16; ++r) {
      const int orow = (r & 3) + 8 * (r >> 2) + 4 * half;  // D row map (m74/m101)
      const int o = wo + ot * 32 + orow;
      float x = acc[ot][r] + Aoi[o * 256 + i_row] + Aoi[o * 256 + jg] + bias[o];
      xout[o * 65536 + mglob] = x;
      gs[ot][r >> 3] += x;
      gq[ot][r >> 3] += x * x;
    }
  }
  if (tid < 16) sred[tid] = 0.0f;
  __syncthreads();
  #pragma unroll
  for (int ot = 0; ot < 2; ++ot) {
    #pragma unroll
    for (int rg = 0; rg < 2; ++rg) {
      float s = gs[ot][rg], qv = gq[ot][rg];
      for (int off = 32; off > 0; off >>= 1) {
        s += __shfl_xor(s, off, 64);
        qv += __shfl_xor(qv, off, 64);
      }
      if (lane == 0) {
        const int g = (wo >> 4) + ot * 2 + rg;
        atomicAdd(&sred[g], s);
        atomicAdd(&sred[8 + g], qv);
      }
    }
  }
  __syncthreads();
  if (tid < 16) atomicAdd(&stats[tid], sred[tid]);
}

// ---------------- groupnorm + exact gelu, in place ----------------
__global__ void norm_kernel(float* __restrict__ xout,
                            const float* __restrict__ stats,
                            const float* __restrict__ gamma,
                            const float* __restrict__ beta) {
  const int idx = blockIdx.x * 256 + threadIdx.x;
  const int e = idx << 2;
  const int o = e >> 16;
  const int g = o >> 4;
  const float invN = 1.0f / 1048576.0f;  // 16*65536 per group
  const float mean = stats[g] * invN;
  const float var = stats[8 + g] * invN - mean * mean;
  const float inv = rsqrtf(var + 1e-5f);
  const float ga = gamma[o], be = beta[o];
  float4 v = *(float4*)(xout + e);
  float* pv = &v.x;
  #pragma unroll
  for (int t = 0; t < 4; ++t) {
    float xn = (pv[t] - mean) * inv * ga + be;
    pv[t] = 0.5f * xn * (1.0f + erff(xn * 0.70710678118654752f));
  }
  *(float4*)(xout + e) = v;
}

extern "C" void kernel_launch(void* const* d_in, const int* in_sizes, int n_in,
                              void* d_out, int out_size, void* d_ws, size_t ws_size,
                              hipStream_t stream) {
  const float* feats = (const float*)d_in[0];
  const float* W     = (const float*)d_in[1];
  const float* bias  = (const float*)d_in[2];
  const float* gamma = (const float*)d_in[3];
  const float* beta  = (const float*)d_in[4];
  float* out = (float*)d_out;

  ushort* fB = (ushort*)d_ws;
  ushort* wB = fB + NFEAT;
  float* stats = (float*)(wB + NW);
  float* Aoi = stats + 16;
  uint* Wt = (uint*)(Aoi + 32768);

  prep_kernel<<<4480, 256, 0, stream>>>(feats, W, fB, wB, stats, Aoi, Wt);
  gemma_kernel<<<32, 256, 0, stream>>>(fB, wB, Aoi);
  gemm_kernel<<<1024, 256, 0, stream>>>(fB, Wt, bias, Aoi, out, stats);
  norm_kernel<<<8192, 256, 0, stream>>>(out, stats, gamma, beta);
}

// Round 8
// 185.806 us; speedup vs baseline: 2.0649x; 2.0649x over previous
//
#include <hip/hip_runtime.h>
#include <math.h>

typedef unsigned int uint;
typedef unsigned short ushort;

typedef __attribute__((ext_vector_type(8))) __bf16 bf16x8;
typedef __attribute__((ext_vector_type(16))) float floatx16;

#define NFEAT 327680   // 256*1280 feats (bf16)
#define NW    491520   // 128*3840 W (bf16)
#define NWT   327680   // Wt uints (128*2560 bf16 = 1.25 MB fragment-ordered)
// ws: fB bf16[NFEAT] | wB bf16[NW] | stats f32[16] | Aoi f32[128*256] | Wt uint[NWT]

union U4B8 { uint4 u; bf16x8 b; };

__device__ inline ushort f2b(float f) {
  uint u = __float_as_uint(f);
  u += 0x7fffu + ((u >> 16) & 1u);   // RNE
  return (ushort)(u >> 16);
}
__device__ inline float blo(uint u) { return __uint_as_float(u << 16); }
__device__ inline float bhi(uint u) { return __uint_as_float(u & 0xffff0000u); }

#if __has_builtin(__builtin_amdgcn_cvt_pk_bf16_f32)
typedef __attribute__((ext_vector_type(2))) __bf16 bf16x2;
__device__ inline uint cvtpk(float a, float b) {
  bf16x2 r = __builtin_amdgcn_cvt_pk_bf16_f32(a, b);
  return *(uint*)&r;
}
__device__ inline uint cvtpk_abs(float a, float b) { return cvtpk(fabsf(a), fabsf(b)); }
#else
__device__ inline uint cvtpk(float a, float b) {   // round-half-up fallback
  uint au = __float_as_uint(a) + 0x8000u;
  uint bu = __float_as_uint(b) + 0x8000u;
  return __builtin_amdgcn_perm(bu, au, 0x07060302u);
}
__device__ inline uint cvtpk_abs(float a, float b) { return cvtpk(a, b) & 0x7fff7fffu; }
#endif

// ---------------- prep: bf16 conversions, Wt fragment layout, zero stats/Aoi ----
// Wt fragment f = cc*16 + st*8 + term*4 + rg  (1 KB each = 256 uints):
//   uint q in frag: lane l = q>>2, t = q&3
//   -> W row = rg*32 + (l&31), k = cc*32 + st*16 + (l>>5)*8 + t*2, col = 1280 + term*1280 + k
__global__ void prep_kernel(const float* __restrict__ feats,
                            const float* __restrict__ W,
                            ushort* __restrict__ fB,
                            ushort* __restrict__ wB,
                            float* __restrict__ stats,
                            float* __restrict__ Aoi,
                            uint* __restrict__ Wt) {
  int idx = blockIdx.x * 256 + threadIdx.x;   // 4480*256 = 819200 + 327680
  if (blockIdx.x == 0 && threadIdx.x < 16) stats[threadIdx.x] = 0.0f;
  if (idx < 32768) Aoi[idx] = 0.0f;
  if (idx < NFEAT) {
    fB[idx] = f2b(feats[idx]);
  } else if (idx < NFEAT + NW) {
    wB[idx - NFEAT] = f2b(W[idx - NFEAT]);
  } else {
    const uint u = idx - (NFEAT + NW);       // [0, NWT)
    const uint frag = u >> 8, q = u & 255;
    const uint rg = frag & 3, term = (frag >> 2) & 1, st = (frag >> 3) & 1, cc = frag >> 4;
    const uint l = q >> 2, t = q & 3;
    const uint row = rg * 32 + (l & 31);
    const uint k = cc * 32 + st * 16 + (l >> 5) * 8 + t * 2;
    const float* src = W + row * 3840 + 1280 + term * 1280 + k;
    Wt[u] = (uint)f2b(src[0]) | ((uint)f2b(src[1]) << 16);
  }
}

// ---------------- A[o,i] = sum_c Wa[o,c]*f[i,c] ----------------
__global__ __launch_bounds__(256, 2) void gemma_kernel(
    const ushort* __restrict__ fB, const ushort* __restrict__ wB,
    float* __restrict__ Aoi) {
  __shared__ float red[4][4096];
  const int tid = threadIdx.x, lane = tid & 63, w = tid >> 6;
  const int i0 = (blockIdx.x >> 2) << 5;
  const int kq = blockIdx.x & 3;
  const int rr = lane & 31, half = lane >> 5;
  floatx16 a4[4];
  #pragma unroll
  for (int ot = 0; ot < 4; ++ot)
    #pragma unroll
    for (int r = 0; r < 16; ++r) a4[ot][r] = 0.0f;
  const int kbase = kq * 320 + w * 80 + half * 8;
  #pragma unroll
  for (int ks = 0; ks < 5; ++ks) {
    const int k = kbase + ks * 16;
    U4B8 bf; bf.u = *(const uint4*)(fB + (i0 + rr) * 1280 + k);
    #pragma unroll
    for (int ot = 0; ot < 4; ++ot) {
      U4B8 af; af.u = *(const uint4*)(wB + (ot * 32 + rr) * 3840 + k);
      a4[ot] = __builtin_amdgcn_mfma_f32_32x32x16_bf16(af.b, bf.b, a4[ot], 0, 0, 0);
    }
  }
  #pragma unroll
  for (int ot = 0; ot < 4; ++ot)
    #pragma unroll
    for (int r = 0; r < 16; ++r) {
      const int orow = (r & 3) + 8 * (r >> 2) + 4 * half;
      red[w][(ot * 32 + orow) * 32 + rr] = a4[ot][r];
    }
  __syncthreads();
  for (int e = tid; e < 4096; e += 256) {
    float s = red[0][e] + red[1][e] + red[2][e] + red[3][e];
    atomicAdd(&Aoi[(e >> 5) * 256 + i0 + (e & 31)], s);
  }
}

// ---------------- main fused GEMM: diff+had, K=2560, NO LDS / NO K-LOOP BARRIERS --
// grid 1024: i = blk>>2, j0 = (blk&3)*64; 4 waves 2x2 (wo=(w>>1)*64, wm=(w&1)*32),
// wave tile 64o x 32m. W A-fragments loaded JUST-IN-TIME from L1/L2-resident Wt
// (fragment-ordered; each load = contiguous 1 KB, wave-uniform base + lane*16).
// Register-disciplined: no prefetch arrays -> ~92 live unified regs, no spill
// at launch_bounds(256,4). Latency hidden by 16 waves/CU TLP.
__global__ __launch_bounds__(256, 4) void gemm_kernel(
    const ushort* __restrict__ fB, const uint* __restrict__ Wt,
    const float* __restrict__ bias, const float* __restrict__ Aoi,
    float* __restrict__ xout, float* __restrict__ stats) {
  __shared__ float sred[16];

  const int tid = threadIdx.x;
  const int blk = blockIdx.x;
  const int i_row = blk >> 2;
  const int j0 = (blk & 3) << 6;
  const int lane = tid & 63;
  const int w = tid >> 6;
  const int wo = (w >> 1) << 6;
  const int wm = (w & 1) << 5;
  const int rr = lane & 31;
  const int half = lane >> 5;
  const int rg0 = wo >> 5;           // 0 or 2

  const ushort* fip = fB + i_row * 1280 + half * 8;
  const ushort* fjp = fB + (j0 + wm + rr) * 1280 + half * 8;

  floatx16 acc[2];
  #pragma unroll
  for (int a = 0; a < 2; ++a)
    #pragma unroll
    for (int r = 0; r < 16; ++r) acc[a][r] = 0.0f;

  for (int cc = 0; cc < 40; ++cc) {
    // wave-uniform chunk base (scalar strength-reduced) + lane offset
    const uint* wc = Wt + cc * 4096 + rg0 * 256 + lane * 4;
    const int cb = cc << 5;          // ushort offset into fi/fj rows
    #pragma unroll
    for (int st = 0; st < 2; ++st) {
      // 4 W fragments JIT (term0/ot0, term0/ot1, term1/ot0, term1/ot1)
      U4B8 wd0, wd1, wh0, wh1;
      wd0.u = *(const uint4*)(wc + st * 2048);
      wd1.u = *(const uint4*)(wc + st * 2048 + 256);
      wh0.u = *(const uint4*)(wc + st * 2048 + 1024);
      wh1.u = *(const uint4*)(wc + st * 2048 + 1280);
      const uint4 vi = *(const uint4*)(fip + cb + st * 16);
      const uint4 vj = *(const uint4*)(fjp + cb + st * 16);
      // build diff/had B-fragments in registers
      U4B8 dfr, hfr;
      {
        uint iu[4] = {vi.x, vi.y, vi.z, vi.w};
        uint ju[4] = {vj.x, vj.y, vj.z, vj.w};
        uint* pd = &dfr.u.x; uint* ph = &hfr.u.x;
        #pragma unroll
        for (int t = 0; t < 4; ++t) {
          float i0 = blo(iu[t]), i1 = bhi(iu[t]);
          float j0f = blo(ju[t]), j1f = bhi(ju[t]);
          pd[t] = cvtpk_abs(i0 - j0f, i1 - j1f);
          ph[t] = cvtpk(i0 * j0f, i1 * j1f);
        }
      }
      acc[0] = __builtin_amdgcn_mfma_f32_32x32x16_bf16(wd0.b, dfr.b, acc[0], 0, 0, 0);
      acc[1] = __builtin_amdgcn_mfma_f32_32x32x16_bf16(wd1.b, dfr.b, acc[1], 0, 0, 0);
      acc[0] = __builtin_amdgcn_mfma_f32_32x32x16_bf16(wh0.b, hfr.b, acc[0], 0, 0, 0);
      acc[1] = __builtin_amdgcn_mfma_f32_32x32x16_bf16(wh1.b, hfr.b, acc[1], 0, 0, 0);
    }
  }

  // epilogue: add A[o,i]+A[o,j]+b[o], store, group stats
  float gs[2][2] = {{0.f, 0.f}, {0.f, 0.f}};
  float gq[2][2] = {{0.f, 0.f}, {0.f, 0.f}};
  const int jg = j0 + wm + rr;
  const int mglob = i_row * 256 + jg;
  #pragma unroll
  for (int ot = 0; ot < 2; ++ot) {
    #pragma unroll
    for (int r = 0; r < 16; ++r) {
      const int orow = (r & 3) + 8 * (r >> 2) + 4 * half;  // D row map (m74/m101)
      const int o = wo + ot * 32 + orow;
      float x = acc[ot][r] + Aoi[o * 256 + i_row] + Aoi[o * 256 + jg] + bias[o];
      xout[o * 65536 + mglob] = x;
      gs[ot][r >> 3] += x;
      gq[ot][r >> 3] += x * x;
    }
  }
  if (tid < 16) sred[tid] = 0.0f;
  __syncthreads();
  #pragma unroll
  for (int ot = 0; ot < 2; ++ot) {
    #pragma unroll
    for (int rg = 0; rg < 2; ++rg) {
      float s = gs[ot][rg], qv = gq[ot][rg];
      for (int off = 32; off > 0; off >>= 1) {
        s += __shfl_xor(s, off, 64);
        qv += __shfl_xor(qv, off, 64);
      }
      if (lane == 0) {
        const int g = (wo >> 4) + ot * 2 + rg;
        atomicAdd(&sred[g], s);
        atomicAdd(&sred[8 + g], qv);
      }
    }
  }
  __syncthreads();
  if (tid < 16) atomicAdd(&stats[tid], sred[tid]);
}

// ---------------- groupnorm + exact gelu, in place ----------------
__global__ void norm_kernel(float* __restrict__ xout,
                            const float* __restrict__ stats,
                            const float* __restrict__ gamma,
                            const float* __restrict__ beta) {
  const int idx = blockIdx.x * 256 + threadIdx.x;
  const int e = idx << 2;
  const int o = e >> 16;
  const int g = o >> 4;
  const float invN = 1.0f / 1048576.0f;  // 16*65536 per group
  const float mean = stats[g] * invN;
  const float var = stats[8 + g] * invN - mean * mean;
  const float inv = rsqrtf(var + 1e-5f);
  const float ga = gamma[o], be = beta[o];
  float4 v = *(float4*)(xout + e);
  float* pv = &v.x;
  #pragma unroll
  for (int t = 0; t < 4; ++t) {
    float xn = (pv[t] - mean) * inv * ga + be;
    pv[t] = 0.5f * xn * (1.0f + erff(xn * 0.70710678118654752f));
  }
  *(float4*)(xout + e) = v;
}

extern "C" void kernel_launch(void* const* d_in, const int* in_sizes, int n_in,
                              void* d_out, int out_size, void* d_ws, size_t ws_size,
                              hipStream_t stream) {
  const float* feats = (const float*)d_in[0];
  const float* W     = (const float*)d_in[1];
  const float* bias  = (const float*)d_in[2];
  const float* gamma = (const float*)d_in[3];
  const float* beta  = (const float*)d_in[4];
  float* out = (float*)d_out;

  ushort* fB = (ushort*)d_ws;
  ushort* wB = fB + NFEAT;
  float* stats = (float*)(wB + NW);
  float* Aoi = stats + 16;
  uint* Wt = (uint*)(Aoi + 32768);

  prep_kernel<<<4480, 256, 0, stream>>>(feats, W, fB, wB, stats, Aoi, Wt);
  gemma_kernel<<<32, 256, 0, stream>>>(fB, wB, Aoi);
  gemm_kernel<<<1024, 256, 0, stream>>>(fB, Wt, bias, Aoi, out, stats);
  norm_kernel<<<8192, 256, 0, stream>>>(out, stats, gamma, beta);
}